// Round 7
// baseline (36.737 us; speedup 1.0000x reference)
//
#include <hip/hip_runtime.h>
#include <stdint.h>

#define BATCH 64
#define MDIM 512
#define KDIM 256
#define BT   128      // A row-strip height, B tile width
#define NTN  4        // col tiles per block
#define NBLK 256      // persistent: 1 block per CU

typedef __attribute__((ext_vector_type(8))) short short8;
typedef __attribute__((ext_vector_type(4))) float f32x4;
typedef __attribute__((ext_vector_type(4))) unsigned int u32x4;

// HW packed f32->bf16 RNE (no builtin on gfx950; single instr)
__device__ __forceinline__ unsigned int cvt_pk(float lo, float hi) {
  unsigned int r;
  asm("v_cvt_pk_bf16_f32 %0, %1, %2" : "=v"(r) : "v"(lo), "v"(hi));
  return r;
}

// Raw barrier: waits LDS ops only; global loads stay in flight.
#define BARRIER()                                         \
  {                                                       \
    asm volatile("s_waitcnt lgkmcnt(0)" ::: "memory");    \
    __builtin_amdgcn_s_barrier();                         \
    asm volatile("" ::: "memory");                        \
  }

#define SQ4(s_, f) { s_ += (f).x*(f).x + (f).y*(f).y + (f).z*(f).z + (f).w*(f).w; }

__device__ __forceinline__ float waveRedSum(float v) {
  v += __shfl_xor(v, 32);
  v += __shfl_xor(v, 16);
  v += __shfl_xor(v, 8);
  v += __shfl_xor(v, 4);
  v += __shfl_xor(v, 2);
  v += __shfl_xor(v, 1);
  return v;
}

// One block per CU. Block = batch b, A-strip tm (128 rows x K=256).
// A: staged to LDS once -> per-wave full-K register fragments (128 VGPR).
// B: 4 tiles streamed through 2 LDS buffers; staging interleaved with MFMA.
// Main loop: 2 ds_read_b128 per K-step, 1 barrier per tile.
__global__ __launch_bounds__(512, 2) void pot_fused(
    const float* __restrict__ V, const float* __restrict__ Ae,
    float* __restrict__ part) {
  const int pid = blockIdx.x;
  const int L   = (pid & 7) * 32 + (pid >> 3);  // XCD grouping: batch's 4 blocks co-XCD
  const int b   = L >> 2;
  const int tm  = L & 3;

  const int tid  = threadIdx.x;
  const int w    = tid >> 6;       // wave 0..7
  const int lane = tid & 63;
  const int wr   = w >> 2;         // 0..1 : 64-row strip
  const int wc   = w & 3;          // 0..3 : 32-col strip
  const int srow = tid >> 2;       // staging row 0..127
  const int sseg = tid & 3;        // staging seg 0..3
  const int fr   = lane & 15;      // frag row within 16
  const int fk   = lane >> 4;      // frag k-window 0..3

  // 2 x 64KB bf16 buffers (rows of 32 16B units, XOR-swizzled u^(row&7))
  __shared__ short buf[2][BT][KDIM];
  __shared__ float nvs[BT];
  __shared__ float nbs[2][BT];

  const float* Arow = V  + ((size_t)b * MDIM + tm * BT + srow) * KDIM;
  const float* Brow = Ae + ((size_t)b * MDIM + srow) * KDIM;

  // ---------------- prologue: stage A -> buf[1], A-norms ----------------
  {
    float4 st[16];
#pragma unroll
    for (int i = 0; i < 8; ++i) {
      const float4* p = reinterpret_cast<const float4*>(Arow + (sseg + 4 * i) * 8);
      st[2 * i] = p[0]; st[2 * i + 1] = p[1];
    }
    float sq = 0.f;
#pragma unroll
    for (int i = 0; i < 8; ++i) {
      const int u = (sseg + 4 * i) ^ (srow & 7);
      u32x4 wv;
      wv[0] = cvt_pk(st[2 * i].x, st[2 * i].y);
      wv[1] = cvt_pk(st[2 * i].z, st[2 * i].w);
      wv[2] = cvt_pk(st[2 * i + 1].x, st[2 * i + 1].y);
      wv[3] = cvt_pk(st[2 * i + 1].z, st[2 * i + 1].w);
      SQ4(sq, st[2 * i]); SQ4(sq, st[2 * i + 1]);
      *reinterpret_cast<u32x4*>(&buf[1][srow][u * 8]) = wv;
    }
    sq += __shfl_xor(sq, 1); sq += __shfl_xor(sq, 2);
    if (sseg == 0) nvs[srow] = 0.5f * sq;
  }

  // issue B0 loads (in flight across barrier #1)
  float4 b0st[16];
#pragma unroll
  for (int i = 0; i < 8; ++i) {
    const float4* p = reinterpret_cast<const float4*>(Brow + (sseg + 4 * i) * 8);
    b0st[2 * i] = p[0]; b0st[2 * i + 1] = p[1];
  }
  BARRIER();  // #1: A-tile + nvs visible

  // write B0 -> buf[0], B0-norms
  {
    float sq = 0.f;
#pragma unroll
    for (int i = 0; i < 8; ++i) {
      const int u = (sseg + 4 * i) ^ (srow & 7);
      u32x4 wv;
      wv[0] = cvt_pk(b0st[2 * i].x, b0st[2 * i].y);
      wv[1] = cvt_pk(b0st[2 * i].z, b0st[2 * i].w);
      wv[2] = cvt_pk(b0st[2 * i + 1].x, b0st[2 * i + 1].y);
      wv[3] = cvt_pk(b0st[2 * i + 1].z, b0st[2 * i + 1].w);
      SQ4(sq, b0st[2 * i]); SQ4(sq, b0st[2 * i + 1]);
      *reinterpret_cast<u32x4*>(&buf[0][srow][u * 8]) = wv;
    }
    sq += __shfl_xor(sq, 1); sq += __shfl_xor(sq, 2);
    if (sseg == 0) nbs[0][srow] = 0.5f * sq;
  }

  // full-K A fragments -> registers (32 short8 = 128 VGPR), from buf[1]
  short8 afr[4][8];
#pragma unroll
  for (int m = 0; m < 4; ++m) {
#pragma unroll
    for (int ks = 0; ks < 8; ++ks) {
      const int row = wr * 64 + m * 16 + fr;
      const int u   = (4 * ks + fk) ^ (row & 7);
      afr[m][ks] = *reinterpret_cast<const short8*>(&buf[1][row][u * 8]);
    }
  }
  BARRIER();  // #2: B0 visible; all A-frag reads of buf[1] complete

  const float k2 = -1.0e-3f * 1.4426950408889634f;  // -1/beta * log2(e)
  float4 bst[2][4];

#pragma unroll
  for (int tn = 0; tn < NTN; ++tn) {
    const int bb = tn & 1;
    const int nb = bb ^ 1;
    const float* Bnx = Brow + (size_t)(tn + 1) * BT * KDIM;

    f32x4 acc[4][2];
#pragma unroll
    for (int m = 0; m < 4; ++m)
#pragma unroll
      for (int n = 0; n < 2; ++n)
        acc[m][n] = (f32x4){0.f, 0.f, 0.f, 0.f};

#define BISSUE(i0, slot)                                                       \
    {                                                                          \
      const float4* p0_ = reinterpret_cast<const float4*>(Bnx + (sseg + 4*(i0)) * 8);     \
      const float4* p1_ = reinterpret_cast<const float4*>(Bnx + (sseg + 4*((i0)+1)) * 8); \
      bst[slot][0] = p0_[0]; bst[slot][1] = p0_[1];                            \
      bst[slot][2] = p1_[0]; bst[slot][3] = p1_[1];                            \
    }
#define BWRITE(i0, slot)                                                       \
    {                                                                          \
      int u_ = (sseg + 4*(i0)) ^ (srow & 7);                                   \
      u32x4 wv_;                                                               \
      wv_[0] = cvt_pk(bst[slot][0].x, bst[slot][0].y);                         \
      wv_[1] = cvt_pk(bst[slot][0].z, bst[slot][0].w);                         \
      wv_[2] = cvt_pk(bst[slot][1].x, bst[slot][1].y);                         \
      wv_[3] = cvt_pk(bst[slot][1].z, bst[slot][1].w);                         \
      SQ4(sqb, bst[slot][0]); SQ4(sqb, bst[slot][1]);                          \
      *reinterpret_cast<u32x4*>(&buf[nb][srow][u_ * 8]) = wv_;                 \
      u_ = (sseg + 4*((i0)+1)) ^ (srow & 7);                                   \
      wv_[0] = cvt_pk(bst[slot][2].x, bst[slot][2].y);                         \
      wv_[1] = cvt_pk(bst[slot][2].z, bst[slot][2].w);                         \
      wv_[2] = cvt_pk(bst[slot][3].x, bst[slot][3].y);                         \
      wv_[3] = cvt_pk(bst[slot][3].z, bst[slot][3].w);                         \
      SQ4(sqb, bst[slot][2]); SQ4(sqb, bst[slot][3]);                          \
      *reinterpret_cast<u32x4*>(&buf[nb][srow][u_ * 8]) = wv_;                 \
    }

    float sqb = 0.f;
    short8 bfr[2][2];
#pragma unroll
    for (int n = 0; n < 2; ++n) {
      const int row = wc * 32 + n * 16 + fr;
      const int u   = fk ^ (row & 7);
      bfr[0][n] = *reinterpret_cast<const short8*>(&buf[bb][row][u * 8]);
    }

#pragma unroll
    for (int ks = 0; ks < 8; ++ks) {
      if (ks < 7) {
#pragma unroll
        for (int n = 0; n < 2; ++n) {
          const int row = wc * 32 + n * 16 + fr;
          const int u   = (4 * (ks + 1) + fk) ^ (row & 7);
          bfr[(ks + 1) & 1][n] =
              *reinterpret_cast<const short8*>(&buf[bb][row][u * 8]);
        }
      }
      if (tn < NTN - 1) {          // weave next-tile staging into this k-loop
        if (ks == 0) { BISSUE(0, 0); }
        if (ks == 2) { BWRITE(0, 0); BISSUE(2, 1); }
        if (ks == 4) { BWRITE(2, 1); BISSUE(4, 0); }
        if (ks == 6) { BWRITE(4, 0); BISSUE(6, 1); }
      }
#pragma unroll
      for (int m = 0; m < 4; ++m)
#pragma unroll
        for (int n = 0; n < 2; ++n)
          acc[m][n] = __builtin_amdgcn_mfma_f32_16x16x32_bf16(
              afr[m][ks], bfr[ks & 1][n], acc[m][n], 0, 0, 0);
    }

    if (tn < NTN - 1) {
      BWRITE(6, 1);
      sqb += __shfl_xor(sqb, 1); sqb += __shfl_xor(sqb, 2);
      if (sseg == 0) nbs[nb][srow] = 0.5f * sqb;
    }

    // epilogue for tile tn: C = hr + hc - dot; T = 2^(C*k2); 4 reductions
    {
      float hr[4][4], hc[2];
#pragma unroll
      for (int m = 0; m < 4; ++m)
#pragma unroll
        for (int r = 0; r < 4; ++r)
          hr[m][r] = nvs[wr * 64 + m * 16 + fk * 4 + r];
#pragma unroll
      for (int n = 0; n < 2; ++n)
        hc[n] = nbs[bb][wc * 32 + n * 16 + fr];

      const bool rowmask = (tm == 0) && (wr == 0) && (fk == 0);
      const bool colmask = (tn == 0) && (wc == 0) && (fr == 0);

      float s0p = 0.f, ctp = 0.f, rsp = 0.f, csp = 0.f;
#pragma unroll
      for (int m = 0; m < 4; ++m) {
#pragma unroll
        for (int n = 0; n < 2; ++n) {
#pragma unroll
          for (int r = 0; r < 4; ++r) {
            float Cv = hr[m][r] + hc[n] - acc[m][n][r];
            float T = exp2f(Cv * k2);
            s0p += T;
            ctp += Cv * T;
            if (m == 0 && r == 0) rsp += rowmask ? T : 0.f;  // global row 0
            if (n == 0)           csp += colmask ? T : 0.f;  // global col 0
          }
        }
      }
      s0p = waveRedSum(s0p);
      ctp = waveRedSum(ctp);
      rsp = waveRedSum(rsp);
      csp = waveRedSum(csp);
      if (lane == 0) {
        float* p = part + (((size_t)(L * NTN + tn)) * 8 + w) * 4;
        p[0] = s0p; p[1] = ctp; p[2] = rsp; p[3] = csp;
      }
    }
    BARRIER();  // next tile's buffer (and nbs) ready; prior reads complete
#undef BISSUE
#undef BWRITE
  }
}

// One wave; thread b = batch b: deterministic reduce over tm x tn x wave,
// 10-iter scalar recurrence, batch mean.
__global__ __launch_bounds__(64) void pot_finalize(
    const float* __restrict__ part, float* __restrict__ out) {
  const int b = threadIdx.x;
  float S0 = 0.f, CT = 0.f, RS = 0.f, CS = 0.f;
#pragma unroll
  for (int tm = 0; tm < 4; ++tm) {
    const int L = 4 * b + tm;
#pragma unroll
    for (int tn = 0; tn < NTN; ++tn) {
      for (int wv = 0; wv < 8; ++wv) {
        const float* p = part + (((size_t)(L * NTN + tn)) * 8 + wv) * 4;
        S0 += p[0]; CT += p[1]; RS += p[2]; CS += p[3];
      }
    }
  }
  const float a0 = 1.0f / (float)MDIM;
  const float b0 = 1.0f / (float)MDIM;
  const float s  = (float)MDIM;
  float c = s / S0;
#pragma unroll
  for (int i = 0; i < 10; ++i) {
    float ka = fminf(a0 / (c * RS), 1.0f);
    float kb = fminf(b0 / (ka * c * CS), 1.0f);
    c = s * ka * kb / S0;
  }
  float D = c * CT;
  D = waveRedSum(D);
  if (b == 0) out[0] = D * (1.0f / (float)BATCH);
}

extern "C" void kernel_launch(void* const* d_in, const int* in_sizes, int n_in,
                              void* d_out, int out_size, void* d_ws, size_t ws_size,
                              hipStream_t stream) {
  const float* V  = (const float*)d_in[0];   // v_emb [64,512,256] f32
  const float* Ae = (const float*)d_in[1];   // a_emb [64,512,256] f32
  float* out  = (float*)d_out;
  float* part = (float*)d_ws;                // [256][4][8][4] f32 = 128 KiB

  pot_fused<<<dim3(NBLK), 512, 0, stream>>>(V, Ae, part);
  pot_finalize<<<1, 64, 0, stream>>>(part, out);
}